// Round 1
// 8750.945 us; speedup vs baseline: 2.1547x; 2.1547x over previous
//
#include <hip/hip_runtime.h>
#include <cstddef>

#define HID 1024
#define H3 3072
#define BATCH 128
#define TT 256
#define N_INH 717   // HID - int(0.3*HID)

// workspace layout (float offsets)
//   W5   : 5 nonzero 1024x1024 blocks, row-major [n][k]        20.97 MB
//   P    : split-K partials [2 btile][48 ntile][8 chunk][64][64] 12.58 MB
//   HBUF : ping-pong compact h [2][128][3072]                    3.15 MB
#define W5_OFF   0
#define P_OFF    5242880u            // 5*1024*1024
#define HBUF_OFF 8388608u            // P_OFF + 2*48*8*4096
#define HBUF_SZ  393216u             // 128*3072

__device__ __forceinline__ float clipf(float w) {
    return fminf(fmaxf(w, 1e-10f), 1.0f);
}

// ---------------------------------------------------------------------------
// Build the 5 nonzero W blocks, each [1024 n][1024 k]:
//  blk0: str<-str  = -s2s_fixed
//  blk1: str<-m1   = mask(<717) * clip(m12str)
//  blk2: thal<-str = clip(str2thal) * (+1 first half cols, -1 second)
//  blk3: m1<-thal  = clip(thal2m1)
//  blk4: m1<-m1    = clip(m12m1) * (+1 cols<717, -1 after)
// ---------------------------------------------------------------------------
__global__ __launch_bounds__(256) void build_w5(
    const float* __restrict__ s2s_fixed,
    const float* __restrict__ s2t_w,
    const float* __restrict__ m2s_w,
    const float* __restrict__ t2m_w,
    const float* __restrict__ m2m_w,
    float* __restrict__ W5)
{
    int j   = blockIdx.x * 256 + threadIdx.x;   // 0..1023
    int row = blockIdx.y;                       // 0..5119
    int blk = row >> 10, ri = row & 1023;
    float v;
    if (blk == 0)      v = -s2s_fixed[ri * HID + j];
    else if (blk == 1) v = (j < N_INH) ? clipf(m2s_w[ri * HID + j]) : 0.0f;
    else if (blk == 2) v = clipf(s2t_w[ri * HID + j]) * ((j < HID / 2) ? 1.0f : -1.0f);
    else if (blk == 3) v = clipf(t2m_w[ri * HID + j]);
    else               v = clipf(m2m_w[ri * HID + j]) * ((j < N_INH) ? 1.0f : -1.0f);
    W5[(size_t)row * HID + j] = v;
}

// ---------------------------------------------------------------------------
// step_a: split-K partial GEMM.
// Grid (320, 2): x = slot -> (ntile, chunk), y = batch tile (64 rows).
//   slots   0..127: str  ntile 0..15, 8 chunks (K: str cols, m1 cols)
//   slots 128..191: thal ntile 16..31, 4 chunks (K: str cols)
//   slots 192..319: m1   ntile 32..47, 8 chunks (K: thal cols, m1 cols)
// Each block: 64b x 64n output partial over K=256, 4x4 per-thread tile,
// double-buffered LDS (one barrier per 32-k step), writes P[tile][chunk].
// ---------------------------------------------------------------------------
__global__ __launch_bounds__(256) void step_a(
    const float* __restrict__ W5,
    const float* __restrict__ h,        // [128][3072] compact
    float* __restrict__ P)
{
    __shared__ float hs[2][32][68];   // [buf][k][b], +4 pad: 16B-aligned rows
    __shared__ float ws[2][32][68];   // [buf][k][n]

    const int tx   = threadIdx.x;
    const int slot = blockIdx.x;
    const int bt   = blockIdx.y;

    int nt, ch;
    if (slot < 128)      { nt = slot >> 3;                ch = slot & 7; }
    else if (slot < 192) { nt = 16 + ((slot - 128) >> 2); ch = (slot - 128) & 3; }
    else                 { nt = 32 + ((slot - 192) >> 3); ch = (slot - 192) & 7; }
    const int rb = nt >> 4;
    int blk, kg;
    if (rb == 0)      { blk = (ch < 4) ? 0 : 1; kg = (ch < 4) ? ch * 256 : 2048 + (ch - 4) * 256; }
    else if (rb == 1) { blk = 2;                kg = ch * 256; }
    else              { blk = (ch < 4) ? 3 : 4; kg = (ch < 4) ? 1024 + ch * 256 : 2048 + (ch - 4) * 256; }
    const int klocal = (ch & 3) * 256;

    // staging: 256 threads load 64 rows x 32 k as float4 (8 lanes/row)
    const int srow = tx >> 3;           // 0..31 (+32 for second half)
    const int sf4  = (tx & 7) << 2;     // k sub-offset 0,4,..,28

    const float* hp = h  + (size_t)(bt * 64 + srow) * H3 + kg + sf4;
    const float* wp = W5 + (size_t)blk * (HID * HID)
                      + (size_t)((nt & 15) * 64 + srow) * HID + klocal + sf4;

    // compute: 16x16 threads, 4 batch x 4 units each
    const int tn = tx & 15, tm = tx >> 4;

    float acc[4][4] = {};
    float4 h0, h1, w0, w1;

#define LOADK(ks) do {                                          \
        h0 = *(const float4*)(hp + (ks) * 32);                  \
        h1 = *(const float4*)(hp + 32 * H3 + (ks) * 32);        \
        w0 = *(const float4*)(wp + (ks) * 32);                  \
        w1 = *(const float4*)(wp + 32 * HID + (ks) * 32);       \
    } while (0)

    LOADK(0);
    for (int ks = 0; ks < 8; ++ks) {
        const int buf = ks & 1;
        // transpose-stage regs -> LDS (safe: last readers of this buf passed
        // the previous barrier)
        hs[buf][sf4 + 0][srow] = h0.x; hs[buf][sf4 + 1][srow] = h0.y;
        hs[buf][sf4 + 2][srow] = h0.z; hs[buf][sf4 + 3][srow] = h0.w;
        hs[buf][sf4 + 0][srow + 32] = h1.x; hs[buf][sf4 + 1][srow + 32] = h1.y;
        hs[buf][sf4 + 2][srow + 32] = h1.z; hs[buf][sf4 + 3][srow + 32] = h1.w;
        ws[buf][sf4 + 0][srow] = w0.x; ws[buf][sf4 + 1][srow] = w0.y;
        ws[buf][sf4 + 2][srow] = w0.z; ws[buf][sf4 + 3][srow] = w0.w;
        ws[buf][sf4 + 0][srow + 32] = w1.x; ws[buf][sf4 + 1][srow + 32] = w1.y;
        ws[buf][sf4 + 2][srow + 32] = w1.z; ws[buf][sf4 + 3][srow + 32] = w1.w;
        if (ks < 7) LOADK(ks + 1);          // prefetch hides under compute
        __syncthreads();
#pragma unroll
        for (int k = 0; k < 32; ++k) {
            float4 a = *(const float4*)&hs[buf][k][tm << 2];
            float4 b = *(const float4*)&ws[buf][k][tn << 2];
            acc[0][0] += a.x * b.x; acc[0][1] += a.x * b.y;
            acc[0][2] += a.x * b.z; acc[0][3] += a.x * b.w;
            acc[1][0] += a.y * b.x; acc[1][1] += a.y * b.y;
            acc[1][2] += a.y * b.z; acc[1][3] += a.y * b.w;
            acc[2][0] += a.z * b.x; acc[2][1] += a.z * b.y;
            acc[2][2] += a.z * b.z; acc[2][3] += a.z * b.w;
            acc[3][0] += a.w * b.x; acc[3][1] += a.w * b.y;
            acc[3][2] += a.w * b.z; acc[3][3] += a.w * b.w;
        }
    }
#undef LOADK

    float* Pt = P + (((size_t)(bt * 48 + nt)) * 8 + ch) * 4096;
#pragma unroll
    for (int i = 0; i < 4; ++i) {
        *(float4*)(Pt + (tm * 4 + i) * 64 + tn * 4) =
            make_float4(acc[i][0], acc[i][1], acc[i][2], acc[i][3]);
    }
}

// ---------------------------------------------------------------------------
// step_b: combine partials + input projection + leak + relu.
// Grid (3, 128): x = row-block, y = batch. Thread handles 4 consecutive n.
// Writes rnn_out[b][t][:] and the compact h buffer for the next step.
// ---------------------------------------------------------------------------
__global__ __launch_bounds__(256) void step_b(
    const float* __restrict__ P,
    const float* __restrict__ x0,       // [B][3072]
    const float* __restrict__ inp,      // [B][T][4]
    const float* __restrict__ iw,       // [4][3072]
    float* __restrict__ rnn_out,        // [B][T][3072]
    float* __restrict__ hnext,          // [B][3072]
    const int t)
{
    const int rbk = blockIdx.x;                 // 0..2
    const int b   = blockIdx.y;                 // 0..127
    const int n   = rbk * HID + threadIdx.x * 4;
    const int nt  = n >> 6;
    const int col = n & 63;
    const int r   = b & 63;
    const int nc  = (rbk == 1) ? 4 : 8;

    const float* Pb = P + ((size_t)((b >> 6) * 48 + nt) * 8) * 4096 + r * 64 + col;
    float4 s = make_float4(0.f, 0.f, 0.f, 0.f);
    for (int c = 0; c < nc; ++c) {
        float4 v = *(const float4*)(Pb + c * 4096);
        s.x += v.x; s.y += v.y; s.z += v.z; s.w += v.w;
    }
    float4 i4 = *(const float4*)(inp + ((size_t)b * TT + t) * 4);
    float4 wa = *(const float4*)(iw + n);
    float4 wb = *(const float4*)(iw + H3 + n);
    float4 wc = *(const float4*)(iw + 2 * H3 + n);
    float4 wd = *(const float4*)(iw + 3 * H3 + n);
    float4 xv = *(const float4*)(x0 + (size_t)b * H3 + n);
    float4 o;
    o.x = fmaxf(0.9f * xv.x + 0.1f * (s.x + i4.x * wa.x + i4.y * wb.x + i4.z * wc.x + i4.w * wd.x), 0.f);
    o.y = fmaxf(0.9f * xv.y + 0.1f * (s.y + i4.x * wa.y + i4.y * wb.y + i4.z * wc.y + i4.w * wd.y), 0.f);
    o.z = fmaxf(0.9f * xv.z + 0.1f * (s.z + i4.x * wa.z + i4.y * wb.z + i4.z * wc.z + i4.w * wd.z), 0.f);
    o.w = fmaxf(0.9f * xv.w + 0.1f * (s.w + i4.x * wa.w + i4.y * wb.w + i4.z * wc.w + i4.w * wd.w), 0.f);
    *(float4*)(rnn_out + (size_t)b * TT * H3 + (size_t)t * H3 + n) = o;
    *(float4*)(hnext + (size_t)b * H3 + n) = o;
}

// ---------------------------------------------------------------------------
// x_out[b,t,:] = x0[b,:]
// ---------------------------------------------------------------------------
__global__ __launch_bounds__(256) void xout_kernel(
    const float* __restrict__ x0, float* __restrict__ x_out)
{
    size_t idx = ((size_t)blockIdx.x * 256 + threadIdx.x) * 4;
    size_t bt = idx / H3;
    int i = (int)(idx - bt * H3);
    int b = (int)(bt >> 8);
    float4 v = *(const float4*)(x0 + (size_t)b * H3 + i);
    *(float4*)(x_out + idx) = v;
}

// ---------------------------------------------------------------------------
// hn_last = rnn_out[:, T-1, :];  x_last = x0
// ---------------------------------------------------------------------------
__global__ __launch_bounds__(256) void last_kernel(
    const float* __restrict__ rnn_out, const float* __restrict__ x0,
    float* __restrict__ hn_last, float* __restrict__ x_last)
{
    int idx = (blockIdx.x * 256 + threadIdx.x) * 4;
    int b = idx / H3;
    int i = idx - b * H3;
    *(float4*)(hn_last + idx) =
        *(const float4*)(rnn_out + (size_t)b * TT * H3 + (size_t)(TT - 1) * H3 + i);
    *(float4*)(x_last + idx) = *(const float4*)(x0 + idx);
}

// ---------------------------------------------------------------------------
// mean_out/std_out: per (b,t) dot over last 1024 channels.
// ---------------------------------------------------------------------------
__global__ __launch_bounds__(256) void tail_kernel(
    const float* __restrict__ rnn_out,
    const float* __restrict__ mW, const float* __restrict__ mb,
    const float* __restrict__ sW, const float* __restrict__ sb,
    float* __restrict__ mean_out, float* __restrict__ std_out)
{
    int wid = blockIdx.x * 4 + (threadIdx.x >> 6);
    int lane = threadIdx.x & 63;
    int b = wid >> 8, t = wid & 255;
    const float* row = rnn_out + (size_t)b * TT * H3 + (size_t)t * H3 + 2048;
    const int j0 = lane * 16;
    float sm = 0.f, ss = 0.f;
#pragma unroll
    for (int e = 0; e < 16; e += 4) {
        float4 v  = *(const float4*)(row + j0 + e);
        float4 wm = *(const float4*)(mW + 2048 + j0 + e);
        float4 wv = *(const float4*)(sW + 2048 + j0 + e);
        sm += v.x * wm.x + v.y * wm.y + v.z * wm.z + v.w * wm.w;
        ss += v.x * wv.x + v.y * wv.y + v.z * wv.z + v.w * wv.w;
    }
#pragma unroll
    for (int off = 32; off; off >>= 1) {
        sm += __shfl_down(sm, off);
        ss += __shfl_down(ss, off);
    }
    if (lane == 0) {
        mean_out[wid] = sm + mb[0];
        std_out[wid]  = ss + sb[0];
    }
}

// ---------------------------------------------------------------------------
extern "C" void kernel_launch(void* const* d_in, const int* in_sizes, int n_in,
                              void* d_out, int out_size, void* d_ws, size_t ws_size,
                              hipStream_t stream)
{
    const float* inp        = (const float*)d_in[0];
    const float* hn         = (const float*)d_in[1];
    const float* x          = (const float*)d_in[2];
    // d_in[3] = str2str_w (unused: str2str_mask is all-zero in the reference)
    const float* str2thal_w = (const float*)d_in[4];
    const float* m12m1_w    = (const float*)d_in[5];
    const float* m12str_w   = (const float*)d_in[6];
    const float* thal2m1_w  = (const float*)d_in[7];
    const float* s2s_fixed  = (const float*)d_in[8];
    const float* iw         = (const float*)d_in[9];
    const float* mean_W     = (const float*)d_in[10];
    const float* mean_b     = (const float*)d_in[11];
    const float* std_W      = (const float*)d_in[12];
    const float* std_b      = (const float*)d_in[13];

    float* out      = (float*)d_out;
    float* mean_out = out;
    float* std_out  = out + 32768;
    float* rnn_out  = out + 65536;
    float* hn_last  = out + 100728832;
    float* x_last   = out + 101122048;
    float* x_out    = out + 101515264;

    float* ws    = (float*)d_ws;
    float* W5    = ws + W5_OFF;
    float* P     = ws + P_OFF;
    float* hbuf0 = ws + HBUF_OFF;
    float* hbuf1 = hbuf0 + HBUF_SZ;

    build_w5<<<dim3(4, 5120), 256, 0, stream>>>(s2s_fixed, str2thal_w, m12str_w,
                                                thal2m1_w, m12m1_w, W5);
    xout_kernel<<<98304, 256, 0, stream>>>(x, x_out);

    for (int t = 0; t < TT; ++t) {
        const float* hsrc = (t == 0) ? hn : ((t & 1) ? hbuf1 : hbuf0);
        float* hdst = ((t + 1) & 1) ? hbuf1 : hbuf0;
        step_a<<<dim3(320, 2), 256, 0, stream>>>(W5, hsrc, P);
        step_b<<<dim3(3, BATCH), 256, 0, stream>>>(P, x, inp, iw, rnn_out, hdst, t);
    }

    last_kernel<<<384, 256, 0, stream>>>(rnn_out, x, hn_last, x_last);
    tail_kernel<<<8192, 256, 0, stream>>>(rnn_out, mean_W, mean_b,
                                          std_W, std_b, mean_out, std_out);
}